// Round 1
// 629.984 us; speedup vs baseline: 1.0185x; 1.0185x over previous
//
#include <hip/hip_runtime.h>

#define ROWS_PER_BLOCK 8
#define TPB 256

// Triple index tables for N=5, K=3, i<=j<=k (35 entries)
__constant__ unsigned char c_I3[35] = {
    0,0,0,0,0,0,0,0,0,0,0,0,0,0,0,
    1,1,1,1,1,1,1,1,1,1,
    2,2,2,2,2,2,
    3,3,3,
    4};
__constant__ unsigned char c_J3[35] = {
    0,0,0,0,0,1,1,1,1,2,2,2,3,3,4,
    1,1,1,1,2,2,2,3,3,4,
    2,2,2,3,3,4,
    3,3,4,
    4};
__constant__ unsigned char c_K3[35] = {
    0,1,2,3,4,1,2,3,4,2,3,4,3,4,4,
    1,2,3,4,2,3,4,3,4,4,
    2,3,4,3,4,4,
    3,4,4,
    4};

__global__ __launch_bounds__(TPB) void bihom_k3_kernel(
    const float* __restrict__ z_re,
    const float* __restrict__ z_im,
    float* __restrict__ out,
    int B)
{
    __shared__ float  s_zre[ROWS_PER_BLOCK * 5];
    __shared__ float  s_zim[ROWS_PER_BLOCK * 5];
    __shared__ float2 s_zz[ROWS_PER_BLOCK * 35];
    __shared__ unsigned int s_pairs[630];   // p | q<<8

    const int tid = threadIdx.x;
    const int row_base = blockIdx.x * ROWS_PER_BLOCK;
    const int rows = min(ROWS_PER_BLOCK, B - row_base);

    // --- stage z for this block's rows ---
    for (int idx = tid; idx < rows * 5; idx += TPB) {
        s_zre[idx] = z_re[row_base * 5 + idx];
        s_zim[idx] = z_im[row_base * 5 + idx];
    }

    // --- build packed pair table (630 pairs p<=q of 35), same decode as before ---
    for (int t = tid; t < 630; t += TPB) {
        // offset(p) = p*(71-p)/2 ; (71-2p)^2 = 5041-8*offset(p) exact at boundaries
        float s = sqrtf((float)(5041 - 8 * t));
        int p = (int)((71.0f - s) * 0.5f);
        int q = p + (t - p * (71 - p) / 2);
        s_pairs[t] = (unsigned)p | ((unsigned)q << 8);
    }
    __syncthreads();

    // --- compute the 35 complex triple products per row ---
    for (int idx = tid; idx < rows * 35; idx += TPB) {
        int r = idx / 35;
        int m = idx - r * 35;
        int i = c_I3[m], j = c_J3[m], k = c_K3[m];
        float ar = s_zre[r * 5 + i], ai = s_zim[r * 5 + i];
        float br = s_zre[r * 5 + j], bi = s_zim[r * 5 + j];
        float cr = s_zre[r * 5 + k], ci = s_zim[r * 5 + k];
        // (a*b) left-assoc, then *c  (matches jnp elementwise complex mul order)
        float tr = ar * br - ai * bi;
        float ti = ar * bi + ai * br;
        float zr = tr * cr - ti * ci;
        float zi = tr * ci + ti * cr;
        s_zz[idx] = make_float2(zr, zi);
    }
    __syncthreads();

    // --- main loop over PAIRS: each pair yields re (always) and im (p<q) ---
    // re  -> out[row*1225 + u]                 (contiguous over u)
    // im  -> out[row*1225 + 630 + (u - p - 1)] (strictIdx(u) = u - p - 1; contiguous
    //                                           over strict pairs in lex order)
    const unsigned obase = (unsigned)row_base * 1225u;
    const int total = rows * 630;
    for (int idx = tid; idx < total; idx += TPB) {
        int r = idx / 630;            // magic-mul
        int u = idx - r * 630;
        unsigned pk = s_pairs[u];
        int p = (int)(pk & 255u);
        int q = (int)(pk >> 8);
        float2 a = s_zz[r * 35 + p];
        float2 b = s_zz[r * 35 + q];
        // zz_p * conj(zz_q): re = ar*br + ai*bi ; im = ai*br - ar*bi
        float re = a.x * b.x + a.y * b.y;
        float im = a.y * b.x - a.x * b.y;
        unsigned orow = obase + (unsigned)r * 1225u;
        out[orow + (unsigned)u] = re;
        if (p != q)
            out[orow + 630u + (unsigned)(u - p - 1)] = im;
    }
}

extern "C" void kernel_launch(void* const* d_in, const int* in_sizes, int n_in,
                              void* d_out, int out_size, void* d_ws, size_t ws_size,
                              hipStream_t stream)
{
    const float* z_re = (const float*)d_in[0];
    const float* z_im = (const float*)d_in[1];
    float* out = (float*)d_out;
    const int B = in_sizes[0] / 5;
    const int blocks = (B + ROWS_PER_BLOCK - 1) / ROWS_PER_BLOCK;
    bihom_k3_kernel<<<blocks, TPB, 0, stream>>>(z_re, z_im, out, B);
}